// Round 16
// baseline (311.801 us; speedup 1.0000x reference)
//
#include <hip/hip_runtime.h>
#include <hip/hip_bf16.h>

typedef __attribute__((ext_vector_type(8))) short bf16x8;
typedef __attribute__((ext_vector_type(4))) float f32x4;

namespace {
constexpr int kC = 256;
constexpr int kN = 2048;
constexpr int kB = 4;
constexpr int kHeads = 7;
constexpr int kOC = kHeads * 64;     // 448
constexpr int kSplit = 4;
constexpr int kMChunk = kN / kSplit; // 512
constexpr float kLog2e = 1.44269504f;
}

static __device__ __forceinline__ float bf2f(ushort u) {
    union { unsigned u; float f; } v; v.u = ((unsigned)u) << 16;
    return v.f;
}
// packed f32x2 -> bf16x2 (RNE); lowers to v_cvt_pk_bf16_f32 when available
static __device__ __forceinline__ unsigned pk_bf16(float a, float b) {
    __hip_bfloat162 h = __float22bfloat162_rn(make_float2(a, b));
    union { __hip_bfloat162 h; unsigned u; } v; v.h = h;
    return v.u;
}
static __device__ __forceinline__ ushort4 pack4bf(float a, float b, float c, float d) {
    union { ushort4 s; uint2 u; } v;
    v.u.x = pk_bf16(a, b); v.u.y = pk_bf16(c, d);
    return v.s;
}
static __device__ __forceinline__ float fexp2(float x) {
#if __has_builtin(__builtin_amdgcn_exp2f)
    return __builtin_amdgcn_exp2f(x);
#else
    return exp2f(x);
#endif
}
// async global->LDS DMA, 16 B per lane. lds dest = l + lane*16 (wave-uniform l).
static __device__ __forceinline__ void g2l16(const ushort* g, ushort* l) {
    __builtin_amdgcn_global_load_lds(
        (const __attribute__((address_space(1))) void*)g,
        (__attribute__((address_space(3))) void*)l,
        16, 0, 0);
}

// ---------------- weight cast fp32 -> bf16 ----------------
__global__ __launch_bounds__(256) void cast_w_kernel(
    const float* __restrict__ Wq, const float* __restrict__ Wk,
    const float* __restrict__ Wv, const float* __restrict__ Wf,
    ushort* __restrict__ wq, ushort* __restrict__ wk,
    ushort* __restrict__ wv, ushort* __restrict__ wf)
{
    int which = blockIdx.y;
    const float* src = which == 0 ? Wq : which == 1 ? Wk : which == 2 ? Wv : Wf;
    ushort* dst      = which == 0 ? wq : which == 1 ? wk : which == 2 ? wv : wf;
    int n = (which == 3) ? kC * kOC : kC * kC;
    int i = (blockIdx.x * 256 + threadIdx.x) * 4;
    if (i < n) {
        float4 v = *(const float4*)(src + i);
        *(ushort4*)(dst + i) = pack4bf(v.x, v.y, v.z, v.w);
    }
}

// ---------------- x transpose+cast: x[b][c][n] fp32 -> xT[b][n][c] bf16 -----
__global__ __launch_bounds__(256) void transpose_kernel(
    const float* __restrict__ x, ushort* __restrict__ xT)
{
    const int nt = blockIdx.x, ct = blockIdx.y, b = blockIdx.z;
    __shared__ float T[64][65];
    const int tid = threadIdx.x;
    const float* xb = x + ((size_t)b * kC + ct * 64) * kN + nt * 64;
#pragma unroll
    for (int p = 0; p < 16; ++p) {
        int idx = p * 256 + tid;
        int cc = idx >> 6, nn = idx & 63;
        T[cc][nn] = xb[(size_t)cc * kN + nn];
    }
    __syncthreads();
    ushort* xTb = xT + ((size_t)b * kN + nt * 64) * kC + ct * 64;
#pragma unroll
    for (int p = 0; p < 4; ++p) {
        int nn = p * 16 + (tid >> 4);
        int c4 = (tid & 15) * 4;
        *(ushort4*)&xTb[(size_t)nn * kC + c4] =
            pack4bf(T[c4 + 0][nn], T[c4 + 1][nn], T[c4 + 2][nn], T[c4 + 3][nn]);
    }
}

// ---------------- QKV projection, 128x128 tile, DMA dbuf 1-barrier ---------
__global__ __launch_bounds__(256, 2) void qkv_kernel(
    const ushort* __restrict__ xT,
    const ushort* __restrict__ Wqb, const ushort* __restrict__ Wkb, const ushort* __restrict__ Wvb,
    const float* __restrict__ sq, const float* __restrict__ bq,
    const float* __restrict__ sk, const float* __restrict__ bk,
    const float* __restrict__ sv, const float* __restrict__ bv,
    ushort* __restrict__ qT, ushort* __restrict__ kT, ushort* __restrict__ vB)
{
    const int nt  = blockIdx.x;          // 16 tiles of 128 n
    const int ot  = blockIdx.y;          // 2 tiles of 128 o
    const int b   = blockIdx.z / 3;
    const int mat = blockIdx.z % 3;
    const ushort* Wb = mat == 0 ? Wqb : mat == 1 ? Wkb : Wvb;
    const float* sm = mat == 0 ? sq : mat == 1 ? sk : sv;
    const float* bm = mat == 0 ? bq : mat == 1 ? bk : bv;

    __shared__ __align__(16) ushort lds[4][128 * 64];   // 64 KB

    const int tid = threadIdx.x;
    const int lane = tid & 63, wav = tid >> 6;
    const int quad = lane >> 4, l16 = lane & 15;

    const ushort* xTb = xT + ((size_t)b * kN + nt * 128) * kC;
    const ushort* Wt  = Wb + (size_t)(ot * 128) * kC;

    f32x4 acc[8][2];
#pragma unroll
    for (int mt = 0; mt < 8; ++mt)
#pragma unroll
        for (int ntt = 0; ntt < 2; ++ntt)
#pragma unroll
            for (int r = 0; r < 4; ++r) acc[mt][ntt][r] = 0.f;

    const int sa   = lane >> 3;           // dest sub-row within 8-row chunk
    const int sblk = (lane & 7) ^ sa;     // source block (swizzle on source)
    auto dmaK = [&](int k0, int buf) {
#pragma unroll
        for (int p = 0; p < 4; ++p) {
            int row = wav * 32 + p * 8 + sa;
            size_t so = (size_t)row * kC + k0 + sblk * 8;
            int dbase = (wav * 32 + p * 8) * 64;
            g2l16(Wt + so,  &lds[buf][dbase]);
            g2l16(xTb + so, &lds[2 + buf][dbase]);
        }
    };

    dmaK(0, 0);
    __syncthreads();

    for (int kt = 0; kt < 4; ++kt) {
        const int cur = kt & 1;
        const bool more = (kt < 3);
        if (more) dmaK((kt + 1) * 64, cur ^ 1);

        const ushort* rowB = (mat < 2) ? lds[cur] : lds[2 + cur];
        const ushort* colB = (mat < 2) ? lds[2 + cur] : lds[cur];
#pragma unroll
        for (int ks = 0; ks < 2; ++ks) {
            bf16x8 bfr[2];
#pragma unroll
            for (int ntt = 0; ntt < 2; ++ntt) {
                int row = wav * 32 + ntt * 16 + l16;
                bfr[ntt] = *(const bf16x8*)&colB[row * 64 + (((ks * 4 + quad) ^ (row & 7)) * 8)];
            }
#pragma unroll
            for (int mt = 0; mt < 8; ++mt) {
                int row = mt * 16 + l16;
                bf16x8 af = *(const bf16x8*)&rowB[row * 64 + (((ks * 4 + quad) ^ (row & 7)) * 8)];
#pragma unroll
                for (int ntt = 0; ntt < 2; ++ntt)
                    acc[mt][ntt] = __builtin_amdgcn_mfma_f32_16x16x32_bf16(
                        af, bfr[ntt], acc[mt][ntt], 0, 0, 0);
            }
        }
        __syncthreads();
    }

    // epilogue: 128x128 transpose gather in lds[0..1] (32 KB, contiguous)
    ushort* sT = &lds[0][0];
    const float qs = (mat == 0) ? kLog2e : 1.f;   // bake log2e into q

    if (mat < 2) {
#pragma unroll
        for (int mt = 0; mt < 8; ++mt) {
            float4 sc4 = *(const float4*)&sm[ot * 128 + mt * 16 + quad * 4];
            float4 bi4 = *(const float4*)&bm[ot * 128 + mt * 16 + quad * 4];
#pragma unroll
            for (int ntt = 0; ntt < 2; ++ntt) {
                int nrow = wav * 32 + ntt * 16 + l16;
                float v0 = fmaf(acc[mt][ntt][0], sc4.x, bi4.x) * qs;
                float v1 = fmaf(acc[mt][ntt][1], sc4.y, bi4.y) * qs;
                float v2 = fmaf(acc[mt][ntt][2], sc4.z, bi4.z) * qs;
                float v3 = fmaf(acc[mt][ntt][3], sc4.w, bi4.w) * qs;
                int cb = (mt * 2 + (quad >> 1)) ^ (nrow & 15);
                *(ushort4*)&sT[nrow * 128 + cb * 8 + (quad & 1) * 4] =
                    pack4bf(v0 > 0.f ? v0 : 0.f, v1 > 0.f ? v1 : 0.f,
                            v2 > 0.f ? v2 : 0.f, v3 > 0.f ? v3 : 0.f);
            }
        }
        __syncthreads();
        ushort* out = (mat == 0) ? qT : kT;
#pragma unroll
        for (int p = 0; p < 8; ++p) {
            int idx = p * 256 + tid;
            int row = idx >> 4, blk = idx & 15;   // row = n_local
            int4 d = *(const int4*)&sT[row * 128 + ((blk ^ (row & 15)) * 8)];
            *(int4*)&out[((size_t)b * kN + nt * 128 + row) * kC + ot * 128 + blk * 8] = d;
        }
    } else {
#pragma unroll
        for (int ntt = 0; ntt < 2; ++ntt) {
            int orow = wav * 32 + ntt * 16 + l16;
            float sc = sm[ot * 128 + orow], bi = bm[ot * 128 + orow];
#pragma unroll
            for (int mt = 0; mt < 8; ++mt) {
                float v0 = fmaf(acc[mt][ntt][0], sc, bi);
                float v1 = fmaf(acc[mt][ntt][1], sc, bi);
                float v2 = fmaf(acc[mt][ntt][2], sc, bi);
                float v3 = fmaf(acc[mt][ntt][3], sc, bi);
                int cb = (mt * 2 + (quad >> 1)) ^ (orow & 15);
                *(ushort4*)&sT[orow * 128 + cb * 8 + (quad & 1) * 4] =
                    pack4bf(v0 > 0.f ? v0 : 0.f, v1 > 0.f ? v1 : 0.f,
                            v2 > 0.f ? v2 : 0.f, v3 > 0.f ? v3 : 0.f);
            }
        }
        __syncthreads();
#pragma unroll
        for (int p = 0; p < 8; ++p) {
            int idx = p * 256 + tid;
            int row = idx >> 4, blk = idx & 15;   // row = o_local
            int4 d = *(const int4*)&sT[row * 128 + ((blk ^ (row & 15)) * 8)];
            *(int4*)&vB[((size_t)b * kC + ot * 128 + row) * kN + nt * 128 + blk * 8] = d;
        }
    }
}

// ---------------- MFMA flash attention: split-4, atomic fp32 accumulate ----
// kSplit=4: 1792 blocks x half work -> 2.33 residency rounds of t/2 vs
// kSplit=2's 2 rounds of t (tail model). Splits are additive because O and l
// are accumulated UNNORMALIZED (O = sum p*V, l = sum p; p = exp2(S') in
// [1, 2^87], sums << fp32 max) via device-scope f32 atomicAdd into Of/Lf
// (zeroed by memset before this kernel). Epilogue: direct per-lane atomics
// (4-lane x 16-n groups land on shared cachelines) -- no LDS transpose.
// LDS = 2x16 (K/V dbuf) + 16 (P) = 48 KB; (256,3) (bigger bounds spill).
__global__ __launch_bounds__(256, 3) void attn_kernel(
    const ushort* __restrict__ qT, const ushort* __restrict__ kT,
    const ushort* __restrict__ vB,
    float* __restrict__ Of, float* __restrict__ Lf)
{
    const int n0 = blockIdx.x * 128;
    const int h  = blockIdx.y;
    const int s  = blockIdx.z & 3;
    const int b  = blockIdx.z >> 2;
    const int tid = threadIdx.x;
    const int lane = tid & 63, wav = tid >> 6;    // 4 waves
    const int quad = lane >> 4, l16 = lane & 15;

    __shared__ __align__(16) ushort sKV[2][8192];   // 2 x 16 KB (K + V)
    __shared__ __align__(16) ushort sP[128 * 64];   // 16 KB (P)

    const ushort* qTb = qT + (size_t)b * kN * kC;
    const ushort* kTb = kT + (size_t)b * kN * kC;
    const ushort* vbb = vB + ((size_t)b * kC + h * 32) * kN;

    const int arr   = wav >> 1;          // 0 = K, 1 = V
    const int rbase = (wav & 1) * 32;

    bf16x8 qf[2][2];
#pragma unroll
    for (int kk = 0; kk < 2; ++kk)
#pragma unroll
        for (int nt2 = 0; nt2 < 2; ++nt2) {
            int ng = n0 + wav * 32 + nt2 * 16 + l16;
            qf[kk][nt2] = *(const bf16x8*)(qTb + (size_t)ng * kC + h * 32 + kk * 32 + quad * 8);
        }

    f32x4 oacc[4][2];
#pragma unroll
    for (int wt = 0; wt < 4; ++wt)
#pragma unroll
        for (int nt2 = 0; nt2 < 2; ++nt2)
#pragma unroll
            for (int r = 0; r < 4; ++r) oacc[wt][nt2][r] = 0.f;
    float li[2] = {0.f, 0.f};

    const int mstart = s * kMChunk;
    const int NIT = kMChunk / 64;     // 8

    const int sa   = lane >> 3;           // dest sub-row within 8-row chunk
    const int sblk = (lane & 7) ^ sa;     // source block (swizzle on source)
    auto dmaTile = [&](int m0, int buf) {
#pragma unroll
        for (int p = 0; p < 4; ++p) {
            int rl = rbase + p * 8 + sa;
            const ushort* src = (arr == 0)
                ? (kTb + (size_t)(m0 + rl) * kC + h * 32 + sblk * 8)
                : (vbb + (size_t)rl * kN + m0 + sblk * 8);
            g2l16(src, &sKV[buf][arr * 4096 + (rbase + p * 8) * 64]);
        }
    };

    dmaTile(mstart, 0);
    __syncthreads();

    for (int it = 0; it < NIT; ++it) {
        const int cur = it & 1;
        const bool more = (it + 1 < NIT);
        if (more) dmaTile(mstart + (it + 1) * 64, cur ^ 1);

        const ushort* sK = &sKV[cur][0];
        const ushort* sV = &sKV[cur][4096];

        // S^T[m][n] = sum_w K[w][m] Q[w][n]  (Q pre-scaled by log2e)
        f32x4 sacc[4][2];
#pragma unroll
        for (int mt = 0; mt < 4; ++mt)
#pragma unroll
            for (int nt2 = 0; nt2 < 2; ++nt2)
#pragma unroll
                for (int r = 0; r < 4; ++r) sacc[mt][nt2][r] = 0.f;
#pragma unroll
        for (int kk = 0; kk < 2; ++kk)
#pragma unroll
            for (int mt = 0; mt < 4; ++mt) {
                int row = mt * 16 + l16;
                bf16x8 af = *(const bf16x8*)&sK[row * 64 + (((kk * 4 + quad) ^ (row & 7)) * 8)];
#pragma unroll
                for (int nt2 = 0; nt2 < 2; ++nt2)
                    sacc[mt][nt2] = __builtin_amdgcn_mfma_f32_16x16x32_bf16(
                        af, qf[kk][nt2], sacc[mt][nt2], 0, 0, 0);
            }

        // softmax numerators: p = exp2(S') directly (no pre-math, no bias)
#pragma unroll
        for (int nt2 = 0; nt2 < 2; ++nt2) {
            int nrow = wav * 32 + nt2 * 16 + l16;
            float sum = 0.f;
#pragma unroll
            for (int mt = 0; mt < 4; ++mt) {
                float p0 = fexp2(sacc[mt][nt2][0]);
                float p1 = fexp2(sacc[mt][nt2][1]);
                float p2 = fexp2(sacc[mt][nt2][2]);
                float p3 = fexp2(sacc[mt][nt2][3]);
                sum += (p0 + p1) + (p2 + p3);
                int bidx = (mt * 2 + (quad >> 1)) ^ (nrow & 7);
                uint2 pk; pk.x = pk_bf16(p0, p1); pk.y = pk_bf16(p2, p3);
                *(uint2*)&sP[nrow * 64 + bidx * 8 + (quad & 1) * 4] = pk;
            }
            sum += __shfl_xor(sum, 16);
            sum += __shfl_xor(sum, 32);
            li[nt2] += sum;
        }

        // O[w][n] += sum_m V[w][m] P[m][n]  (P rows wave-private)
#pragma unroll
        for (int ks = 0; ks < 2; ++ks) {
            bf16x8 pf[2];
#pragma unroll
            for (int nt2 = 0; nt2 < 2; ++nt2) {
                int nr = wav * 32 + nt2 * 16 + l16;
                pf[nt2] = *(const bf16x8*)&sP[nr * 64 + (((ks * 4 + quad) ^ (nr & 7)) * 8)];
            }
#pragma unroll
            for (int wt = 0; wt < 4; ++wt) {
                int wr = wt * 16 + l16;
                bf16x8 vf = *(const bf16x8*)&sV[wr * 64 + (((ks * 4 + quad) ^ (wr & 7)) * 8)];
#pragma unroll
                for (int nt2 = 0; nt2 < 2; ++nt2)
                    oacc[wt][nt2] = __builtin_amdgcn_mfma_f32_16x16x32_bf16(
                        vf, pf[nt2], oacc[wt][nt2], 0, 0, 0);
            }
        }

        __syncthreads();   // drains DMA (vmcnt) + P/K/V LDS ops (lgkm)
    }

    // ---- epilogue: atomic fp32 accumulate of raw O and l ----
    float* Ob = Of + ((size_t)b * kN + n0) * kOC + h * 64;
#pragma unroll
    for (int nt2 = 0; nt2 < 2; ++nt2) {
        int nl = wav * 32 + nt2 * 16 + l16;
        if (quad == 0)
            atomicAdd(Lf + ((size_t)b * kHeads + h) * kN + n0 + nl, li[nt2]);
#pragma unroll
        for (int wt = 0; wt < 4; ++wt)
#pragma unroll
            for (int r = 0; r < 4; ++r)
                atomicAdd(Ob + (size_t)nl * kOC + wt * 16 + quad * 4 + r,
                          oacc[wt][nt2][r]);
    }
}

// ---------------- final projection: normalize-by-l, dbuf 1-barrier ---------
__global__ __launch_bounds__(128, 3) void proj_kernel(
    const float* __restrict__ Of, const float* __restrict__ Lf,
    const ushort* __restrict__ Wfb,
    const float* __restrict__ bf_, const float* __restrict__ sf,
    const float* __restrict__ bff, float* __restrict__ out)
{
    const int nt = blockIdx.x;
    const int ot = blockIdx.y;
    const int b  = blockIdx.z;
    __shared__ __align__(16) ushort sA[2][64 * 64];
    __shared__ __align__(16) ushort sB[2][64 * 64];
    const int tid = threadIdx.x;
    const int lane = tid & 63, wav = tid >> 6;
    const int quad = lane >> 4, l16 = lane & 15;

    const ushort* Wt = Wfb + (size_t)(ot * 64) * kOC;

    f32x4 acc[4][2];
#pragma unroll
    for (int mt = 0; mt < 4; ++mt)
#pragma unroll
        for (int ntt = 0; ntt < 2; ++ntt)
#pragma unroll
            for (int r = 0; r < 4; ++r) acc[mt][ntt][r] = 0.f;

    int4 areg[4];
    float4 o1reg[4], o2reg[4];
    float winv[4];

    auto prefetch = [&](int kt) {
        int k0 = kt * 64;
#pragma unroll
        for (int p = 0; p < 4; ++p) {
            int idx = p * 128 + tid, row = idx >> 3, blk = idx & 7;
            areg[p] = *(const int4*)(Wt + (size_t)row * kOC + k0 + blk * 8);
            int n = nt * 64 + row;
            const float* ofp = Of + ((size_t)b * kN + n) * kOC + k0 + blk * 8;
            o1reg[p] = *(const float4*)(ofp);
            o2reg[p] = *(const float4*)(ofp + 4);
            winv[p] = 1.f / Lf[((size_t)b * kHeads + kt) * kN + n];
        }
    };
    auto stage = [&](int buf) {
#pragma unroll
        for (int p = 0; p < 4; ++p) {
            int idx = p * 128 + tid, row = idx >> 3, blk = idx & 7;
            *(int4*)&sA[buf][row * 64 + ((blk ^ (row & 7)) * 8)] = areg[p];
            float iv = winv[p];
            int4 o;
            o.x = (int)pk_bf16(o1reg[p].x * iv, o1reg[p].y * iv);
            o.y = (int)pk_bf16(o1reg[p].z * iv, o1reg[p].w * iv);
            o.z = (int)pk_bf16(o2reg[p].x * iv, o2reg[p].y * iv);
            o.w = (int)pk_bf16(o2reg[p].z * iv, o2reg[p].w * iv);
            *(int4*)&sB[buf][row * 64 + ((blk ^ (row & 7)) * 8)] = o;
        }
    };

    prefetch(0);
    stage(0);
    __syncthreads();

    for (int kt = 0; kt < 7; ++kt) {
        const int cur = kt & 1;
        const bool more = (kt < 6);
        if (more) prefetch(kt + 1);
#pragma unroll
        for (int ks = 0; ks < 2; ++ks) {
            bf16x8 bfr[2];
#pragma unroll
            for (int ntt = 0; ntt < 2; ++ntt) {
                int row = wav * 32 + ntt * 16 + l16;
                bfr[ntt] = *(const bf16x8*)&sB[cur][row * 64 + (((ks * 4 + quad) ^ (row & 7)) * 8)];
            }
#pragma unroll
            for (int mt = 0; mt < 4; ++mt) {
                int row = mt * 16 + l16;
                bf16x8 af = *(const bf16x8*)&sA[cur][row * 64 + (((ks * 4 + quad) ^ (row & 7)) * 8)];
#pragma unroll
                for (int ntt = 0; ntt < 2; ++ntt)
                    acc[mt][ntt] = __builtin_amdgcn_mfma_f32_16x16x32_bf16(
                        af, bfr[ntt], acc[mt][ntt], 0, 0, 0);
            }
        }
        if (more) stage(cur ^ 1);
        __syncthreads();
    }
#pragma unroll
    for (int mt = 0; mt < 4; ++mt)
#pragma unroll
        for (int r = 0; r < 4; ++r) {
            int o = ot * 64 + mt * 16 + quad * 4 + r;
            float bfv = bf_[o], sfv = sf[o], bffv = bff[o];
#pragma unroll
            for (int ntt = 0; ntt < 2; ++ntt) {
                int n = nt * 64 + wav * 32 + ntt * 16 + l16;
                float y = fmaf(acc[mt][ntt][r] + bfv, sfv, bffv);
                out[((size_t)b * kC + o) * kN + n] = y > 0.f ? y : 0.f;
            }
        }
}

extern "C" void kernel_launch(void* const* d_in, const int* in_sizes, int n_in,
                              void* d_out, int out_size, void* d_ws, size_t ws_size,
                              hipStream_t stream) {
    const float* x   = (const float*)d_in[0];
    const float* Wq  = (const float*)d_in[1];
    const float* sq  = (const float*)d_in[2];
    const float* bq  = (const float*)d_in[3];
    const float* Wk  = (const float*)d_in[4];
    const float* sk  = (const float*)d_in[5];
    const float* bk  = (const float*)d_in[6];
    const float* Wv  = (const float*)d_in[7];
    const float* sv  = (const float*)d_in[8];
    const float* bv  = (const float*)d_in[9];
    const float* Wf  = (const float*)d_in[10];
    const float* bf_ = (const float*)d_in[11];
    const float* sf  = (const float*)d_in[12];
    const float* bff = (const float*)d_in[13];
    float* out = (float*)d_out;

    char* ws = (char*)d_ws;
    ushort* xT  = (ushort*)(ws);                         // 4,194,304
    ushort* Wqb = (ushort*)(ws + 4194304);               // 131,072
    ushort* Wkb = (ushort*)(ws + 4325376);               // 131,072
    ushort* Wvb = (ushort*)(ws + 4456448);               // 131,072
    ushort* Wfb = (ushort*)(ws + 4587520);               // 229,376
    ushort* qT  = (ushort*)(ws + 4816896);               // 4,194,304
    ushort* kT  = (ushort*)(ws + 9011200);               // 4,194,304
    ushort* vB  = (ushort*)(ws + 13205504);              // 4,194,304
    float*  Of  = (float*)(ws + 17399808);               // 14,680,064 (fp32)
    float*  Lf  = (float*)(ws + 32079872);               // 229,376 (fp32)
    // total 32,309,248 bytes

    cast_w_kernel<<<dim3(112, 4), 256, 0, stream>>>(Wq, Wk, Wv, Wf, Wqb, Wkb, Wvb, Wfb);
    transpose_kernel<<<dim3(kN / 64, kC / 64, kB), 256, 0, stream>>>(x, xT);
    // zero the atomic accumulators (Of + Lf contiguous)
    hipMemsetAsync(ws + 17399808, 0, 14680064 + 229376, stream);
    qkv_kernel<<<dim3(kN / 128, kC / 128, kB * 3), 256, 0, stream>>>(
        xT, Wqb, Wkb, Wvb, sq, bq, sk, bk, sv, bv, qT, kT, vB);
    attn_kernel<<<dim3(kN / 128, kHeads, kB * kSplit), 256, 0, stream>>>(
        qT, kT, vB, Of, Lf);
    proj_kernel<<<dim3(kN / 64, kC / 64, kB), 128, 0, stream>>>(
        Of, Lf, Wfb, bf_, sf, bff, out);
}

// Round 17
// 164.955 us; speedup vs baseline: 1.8902x; 1.8902x over previous
//
#include <hip/hip_runtime.h>
#include <hip/hip_bf16.h>

typedef __attribute__((ext_vector_type(8))) short bf16x8;
typedef __attribute__((ext_vector_type(4))) float f32x4;

namespace {
constexpr int kC = 256;
constexpr int kN = 2048;
constexpr int kB = 4;
constexpr int kHeads = 7;
constexpr int kOC = kHeads * 64;     // 448
constexpr int kSplit = 2;
constexpr int kMChunk = kN / kSplit; // 1024
constexpr float kLog2e = 1.44269504f;
}

static __device__ __forceinline__ float bf2f(ushort u) {
    union { unsigned u; float f; } v; v.u = ((unsigned)u) << 16;
    return v.f;
}
// packed f32x2 -> bf16x2 (RNE); lowers to v_cvt_pk_bf16_f32 when available
static __device__ __forceinline__ unsigned pk_bf16(float a, float b) {
    __hip_bfloat162 h = __float22bfloat162_rn(make_float2(a, b));
    union { __hip_bfloat162 h; unsigned u; } v; v.h = h;
    return v.u;
}
static __device__ __forceinline__ ushort4 pack4bf(float a, float b, float c, float d) {
    union { ushort4 s; uint2 u; } v;
    v.u.x = pk_bf16(a, b); v.u.y = pk_bf16(c, d);
    return v.s;
}
static __device__ __forceinline__ float fexp2(float x) {
#if __has_builtin(__builtin_amdgcn_exp2f)
    return __builtin_amdgcn_exp2f(x);
#else
    return exp2f(x);
#endif
}
// async global->LDS DMA, 16 B per lane. lds dest = l + lane*16 (wave-uniform l).
static __device__ __forceinline__ void g2l16(const ushort* g, ushort* l) {
    __builtin_amdgcn_global_load_lds(
        (const __attribute__((address_space(1))) void*)g,
        (__attribute__((address_space(3))) void*)l,
        16, 0, 0);
}

// ---------------- weight cast fp32 -> bf16 ----------------
__global__ __launch_bounds__(256) void cast_w_kernel(
    const float* __restrict__ Wq, const float* __restrict__ Wk,
    const float* __restrict__ Wv, const float* __restrict__ Wf,
    ushort* __restrict__ wq, ushort* __restrict__ wk,
    ushort* __restrict__ wv, ushort* __restrict__ wf)
{
    int which = blockIdx.y;
    const float* src = which == 0 ? Wq : which == 1 ? Wk : which == 2 ? Wv : Wf;
    ushort* dst      = which == 0 ? wq : which == 1 ? wk : which == 2 ? wv : wf;
    int n = (which == 3) ? kC * kOC : kC * kC;
    int i = (blockIdx.x * 256 + threadIdx.x) * 4;
    if (i < n) {
        float4 v = *(const float4*)(src + i);
        *(ushort4*)(dst + i) = pack4bf(v.x, v.y, v.z, v.w);
    }
}

// ---------------- x transpose+cast: x[b][c][n] fp32 -> xT[b][n][c] bf16 -----
__global__ __launch_bounds__(256) void transpose_kernel(
    const float* __restrict__ x, ushort* __restrict__ xT)
{
    const int nt = blockIdx.x, ct = blockIdx.y, b = blockIdx.z;
    __shared__ float T[64][65];
    const int tid = threadIdx.x;
    const float* xb = x + ((size_t)b * kC + ct * 64) * kN + nt * 64;
#pragma unroll
    for (int p = 0; p < 16; ++p) {
        int idx = p * 256 + tid;
        int cc = idx >> 6, nn = idx & 63;
        T[cc][nn] = xb[(size_t)cc * kN + nn];
    }
    __syncthreads();
    ushort* xTb = xT + ((size_t)b * kN + nt * 64) * kC + ct * 64;
#pragma unroll
    for (int p = 0; p < 4; ++p) {
        int nn = p * 16 + (tid >> 4);
        int c4 = (tid & 15) * 4;
        *(ushort4*)&xTb[(size_t)nn * kC + c4] =
            pack4bf(T[c4 + 0][nn], T[c4 + 1][nn], T[c4 + 2][nn], T[c4 + 3][nn]);
    }
}

// ---------------- QKV projection, 128x128 tile, DMA dbuf 1-barrier ---------
__global__ __launch_bounds__(256, 2) void qkv_kernel(
    const ushort* __restrict__ xT,
    const ushort* __restrict__ Wqb, const ushort* __restrict__ Wkb, const ushort* __restrict__ Wvb,
    const float* __restrict__ sq, const float* __restrict__ bq,
    const float* __restrict__ sk, const float* __restrict__ bk,
    const float* __restrict__ sv, const float* __restrict__ bv,
    ushort* __restrict__ qT, ushort* __restrict__ kT, ushort* __restrict__ vB)
{
    const int nt  = blockIdx.x;          // 16 tiles of 128 n
    const int ot  = blockIdx.y;          // 2 tiles of 128 o
    const int b   = blockIdx.z / 3;
    const int mat = blockIdx.z % 3;
    const ushort* Wb = mat == 0 ? Wqb : mat == 1 ? Wkb : Wvb;
    const float* sm = mat == 0 ? sq : mat == 1 ? sk : sv;
    const float* bm = mat == 0 ? bq : mat == 1 ? bk : bv;

    __shared__ __align__(16) ushort lds[4][128 * 64];   // 64 KB

    const int tid = threadIdx.x;
    const int lane = tid & 63, wav = tid >> 6;
    const int quad = lane >> 4, l16 = lane & 15;

    const ushort* xTb = xT + ((size_t)b * kN + nt * 128) * kC;
    const ushort* Wt  = Wb + (size_t)(ot * 128) * kC;

    f32x4 acc[8][2];
#pragma unroll
    for (int mt = 0; mt < 8; ++mt)
#pragma unroll
        for (int ntt = 0; ntt < 2; ++ntt)
#pragma unroll
            for (int r = 0; r < 4; ++r) acc[mt][ntt][r] = 0.f;

    const int sa   = lane >> 3;           // dest sub-row within 8-row chunk
    const int sblk = (lane & 7) ^ sa;     // source block (swizzle on source)
    auto dmaK = [&](int k0, int buf) {
#pragma unroll
        for (int p = 0; p < 4; ++p) {
            int row = wav * 32 + p * 8 + sa;
            size_t so = (size_t)row * kC + k0 + sblk * 8;
            int dbase = (wav * 32 + p * 8) * 64;
            g2l16(Wt + so,  &lds[buf][dbase]);
            g2l16(xTb + so, &lds[2 + buf][dbase]);
        }
    };

    dmaK(0, 0);
    __syncthreads();

    for (int kt = 0; kt < 4; ++kt) {
        const int cur = kt & 1;
        const bool more = (kt < 3);
        if (more) dmaK((kt + 1) * 64, cur ^ 1);

        const ushort* rowB = (mat < 2) ? lds[cur] : lds[2 + cur];
        const ushort* colB = (mat < 2) ? lds[2 + cur] : lds[cur];
#pragma unroll
        for (int ks = 0; ks < 2; ++ks) {
            bf16x8 bfr[2];
#pragma unroll
            for (int ntt = 0; ntt < 2; ++ntt) {
                int row = wav * 32 + ntt * 16 + l16;
                bfr[ntt] = *(const bf16x8*)&colB[row * 64 + (((ks * 4 + quad) ^ (row & 7)) * 8)];
            }
#pragma unroll
            for (int mt = 0; mt < 8; ++mt) {
                int row = mt * 16 + l16;
                bf16x8 af = *(const bf16x8*)&rowB[row * 64 + (((ks * 4 + quad) ^ (row & 7)) * 8)];
#pragma unroll
                for (int ntt = 0; ntt < 2; ++ntt)
                    acc[mt][ntt] = __builtin_amdgcn_mfma_f32_16x16x32_bf16(
                        af, bfr[ntt], acc[mt][ntt], 0, 0, 0);
            }
        }
        __syncthreads();
    }

    // epilogue: 128x128 transpose gather in lds[0..1] (32 KB, contiguous)
    ushort* sT = &lds[0][0];
    const float qs = (mat == 0) ? kLog2e : 1.f;   // bake log2e into q

    if (mat < 2) {
#pragma unroll
        for (int mt = 0; mt < 8; ++mt) {
            float4 sc4 = *(const float4*)&sm[ot * 128 + mt * 16 + quad * 4];
            float4 bi4 = *(const float4*)&bm[ot * 128 + mt * 16 + quad * 4];
#pragma unroll
            for (int ntt = 0; ntt < 2; ++ntt) {
                int nrow = wav * 32 + ntt * 16 + l16;
                float v0 = fmaf(acc[mt][ntt][0], sc4.x, bi4.x) * qs;
                float v1 = fmaf(acc[mt][ntt][1], sc4.y, bi4.y) * qs;
                float v2 = fmaf(acc[mt][ntt][2], sc4.z, bi4.z) * qs;
                float v3 = fmaf(acc[mt][ntt][3], sc4.w, bi4.w) * qs;
                int cb = (mt * 2 + (quad >> 1)) ^ (nrow & 15);
                *(ushort4*)&sT[nrow * 128 + cb * 8 + (quad & 1) * 4] =
                    pack4bf(v0 > 0.f ? v0 : 0.f, v1 > 0.f ? v1 : 0.f,
                            v2 > 0.f ? v2 : 0.f, v3 > 0.f ? v3 : 0.f);
            }
        }
        __syncthreads();
        ushort* out = (mat == 0) ? qT : kT;
#pragma unroll
        for (int p = 0; p < 8; ++p) {
            int idx = p * 256 + tid;
            int row = idx >> 4, blk = idx & 15;   // row = n_local
            int4 d = *(const int4*)&sT[row * 128 + ((blk ^ (row & 15)) * 8)];
            *(int4*)&out[((size_t)b * kN + nt * 128 + row) * kC + ot * 128 + blk * 8] = d;
        }
    } else {
#pragma unroll
        for (int ntt = 0; ntt < 2; ++ntt) {
            int orow = wav * 32 + ntt * 16 + l16;
            float sc = sm[ot * 128 + orow], bi = bm[ot * 128 + orow];
#pragma unroll
            for (int mt = 0; mt < 8; ++mt) {
                float v0 = fmaf(acc[mt][ntt][0], sc, bi);
                float v1 = fmaf(acc[mt][ntt][1], sc, bi);
                float v2 = fmaf(acc[mt][ntt][2], sc, bi);
                float v3 = fmaf(acc[mt][ntt][3], sc, bi);
                int cb = (mt * 2 + (quad >> 1)) ^ (orow & 15);
                *(ushort4*)&sT[orow * 128 + cb * 8 + (quad & 1) * 4] =
                    pack4bf(v0 > 0.f ? v0 : 0.f, v1 > 0.f ? v1 : 0.f,
                            v2 > 0.f ? v2 : 0.f, v3 > 0.f ? v3 : 0.f);
            }
        }
        __syncthreads();
#pragma unroll
        for (int p = 0; p < 8; ++p) {
            int idx = p * 256 + tid;
            int row = idx >> 4, blk = idx & 15;   // row = o_local
            int4 d = *(const int4*)&sT[row * 128 + ((blk ^ (row & 15)) * 8)];
            *(int4*)&vB[((size_t)b * kC + ot * 128 + row) * kN + nt * 128 + blk * 8] = d;
        }
    }
}

// ---------------- MFMA flash attention (R12-exact): Q-tile 128, DMA dbuf ---
// LDS = 2x16 (K/V dbuf) + 16 (P) = 48 KB, 3 blocks/CU. Batched softmax (32
// exps) then batched PV (16 MFMAs). (256,3): natural 84 arch + 32 AGPR = 116
// unified. Probed and rejected: (256,4) spills (R7/R9/R13), 40 KB interleaved
// halves (R14), split-4 atomics (R16, 230 MB RMW). This is the optimum found.
__global__ __launch_bounds__(256, 3) void attn_kernel(
    const ushort* __restrict__ qT, const ushort* __restrict__ kT,
    const ushort* __restrict__ vB,
    ushort* __restrict__ Opart, float* __restrict__ Ls)
{
    const int n0 = blockIdx.x * 128;
    const int h  = blockIdx.y;
    const int s  = blockIdx.z & 1;
    const int b  = blockIdx.z >> 1;
    const int tid = threadIdx.x;
    const int lane = tid & 63, wav = tid >> 6;    // 4 waves
    const int quad = lane >> 4, l16 = lane & 15;

    __shared__ __align__(16) ushort sKV[2][8192];   // 2 x 16 KB (K + V)
    __shared__ __align__(16) ushort sP[128 * 64];   // 16 KB (P / O-transpose)

    const ushort* qTb = qT + (size_t)b * kN * kC;
    const ushort* kTb = kT + (size_t)b * kN * kC;
    const ushort* vbb = vB + ((size_t)b * kC + h * 32) * kN;

    const int arr   = wav >> 1;          // 0 = K, 1 = V
    const int rbase = (wav & 1) * 32;

    bf16x8 qf[2][2];
#pragma unroll
    for (int kk = 0; kk < 2; ++kk)
#pragma unroll
        for (int nt2 = 0; nt2 < 2; ++nt2) {
            int ng = n0 + wav * 32 + nt2 * 16 + l16;
            qf[kk][nt2] = *(const bf16x8*)(qTb + (size_t)ng * kC + h * 32 + kk * 32 + quad * 8);
        }

    f32x4 oacc[4][2];
#pragma unroll
    for (int wt = 0; wt < 4; ++wt)
#pragma unroll
        for (int nt2 = 0; nt2 < 2; ++nt2)
#pragma unroll
            for (int r = 0; r < 4; ++r) oacc[wt][nt2][r] = 0.f;
    float li[2] = {0.f, 0.f};

    const int mstart = s * kMChunk;
    const int NIT = kMChunk / 64;     // 16

    const int sa   = lane >> 3;           // dest sub-row within 8-row chunk
    const int sblk = (lane & 7) ^ sa;     // source block (swizzle on source)
    auto dmaTile = [&](int m0, int buf) {
#pragma unroll
        for (int p = 0; p < 4; ++p) {
            int rl = rbase + p * 8 + sa;
            const ushort* src = (arr == 0)
                ? (kTb + (size_t)(m0 + rl) * kC + h * 32 + sblk * 8)
                : (vbb + (size_t)rl * kN + m0 + sblk * 8);
            g2l16(src, &sKV[buf][arr * 4096 + (rbase + p * 8) * 64]);
        }
    };

    dmaTile(mstart, 0);
    __syncthreads();

    for (int it = 0; it < NIT; ++it) {
        const int cur = it & 1;
        const bool more = (it + 1 < NIT);
        if (more) dmaTile(mstart + (it + 1) * 64, cur ^ 1);

        const ushort* sK = &sKV[cur][0];
        const ushort* sV = &sKV[cur][4096];

        // S^T[m][n] = sum_w K[w][m] Q[w][n]  (Q pre-scaled by log2e)
        f32x4 sacc[4][2];
#pragma unroll
        for (int mt = 0; mt < 4; ++mt)
#pragma unroll
            for (int nt2 = 0; nt2 < 2; ++nt2)
#pragma unroll
                for (int r = 0; r < 4; ++r) sacc[mt][nt2][r] = 0.f;
#pragma unroll
        for (int kk = 0; kk < 2; ++kk)
#pragma unroll
            for (int mt = 0; mt < 4; ++mt) {
                int row = mt * 16 + l16;
                bf16x8 af = *(const bf16x8*)&sK[row * 64 + (((kk * 4 + quad) ^ (row & 7)) * 8)];
#pragma unroll
                for (int nt2 = 0; nt2 < 2; ++nt2)
                    sacc[mt][nt2] = __builtin_amdgcn_mfma_f32_16x16x32_bf16(
                        af, qf[kk][nt2], sacc[mt][nt2], 0, 0, 0);
            }

        // softmax numerators: p = exp2(S') directly (no pre-math, no bias)
#pragma unroll
        for (int nt2 = 0; nt2 < 2; ++nt2) {
            int nrow = wav * 32 + nt2 * 16 + l16;
            float sum = 0.f;
#pragma unroll
            for (int mt = 0; mt < 4; ++mt) {
                float p0 = fexp2(sacc[mt][nt2][0]);
                float p1 = fexp2(sacc[mt][nt2][1]);
                float p2 = fexp2(sacc[mt][nt2][2]);
                float p3 = fexp2(sacc[mt][nt2][3]);
                sum += (p0 + p1) + (p2 + p3);
                int bidx = (mt * 2 + (quad >> 1)) ^ (nrow & 7);
                uint2 pk; pk.x = pk_bf16(p0, p1); pk.y = pk_bf16(p2, p3);
                *(uint2*)&sP[nrow * 64 + bidx * 8 + (quad & 1) * 4] = pk;
            }
            sum += __shfl_xor(sum, 16);
            sum += __shfl_xor(sum, 32);
            li[nt2] += sum;
        }

        // O[w][n] += sum_m V[w][m] P[m][n]  (P rows wave-private)
#pragma unroll
        for (int ks = 0; ks < 2; ++ks) {
            bf16x8 pf[2];
#pragma unroll
            for (int nt2 = 0; nt2 < 2; ++nt2) {
                int nr = wav * 32 + nt2 * 16 + l16;
                pf[nt2] = *(const bf16x8*)&sP[nr * 64 + (((ks * 4 + quad) ^ (nr & 7)) * 8)];
            }
#pragma unroll
            for (int wt = 0; wt < 4; ++wt) {
                int wr = wt * 16 + l16;
                bf16x8 vf = *(const bf16x8*)&sV[wr * 64 + (((ks * 4 + quad) ^ (wr & 7)) * 8)];
#pragma unroll
                for (int nt2 = 0; nt2 < 2; ++nt2)
                    oacc[wt][nt2] = __builtin_amdgcn_mfma_f32_16x16x32_bf16(
                        vf, pf[nt2], oacc[wt][nt2], 0, 0, 0);
            }
        }

        __syncthreads();   // drains DMA (vmcnt) + P/K/V LDS ops (lgkm)
    }

    // ---- epilogue: stats + LDS-transpose O + coalesced store ----
#pragma unroll
    for (int nt2 = 0; nt2 < 2; ++nt2) {
        if (quad == 0) {
            int n = n0 + wav * 32 + nt2 * 16 + l16;
            size_t si = ((size_t)(s * kB + b) * kHeads + h) * kN + n;
            Ls[si] = li[nt2];
        }
    }
    ushort* sT = sP;
#pragma unroll
    for (int wt = 0; wt < 4; ++wt)
#pragma unroll
        for (int nt2 = 0; nt2 < 2; ++nt2) {
            float inv = 1.f / li[nt2];
            int nrow = wav * 32 + nt2 * 16 + l16;
            int cb = (wt * 2 + (quad >> 1)) ^ (nrow & 7);
            *(ushort4*)&sT[nrow * 64 + cb * 8 + (quad & 1) * 4] =
                pack4bf(oacc[wt][nt2][0] * inv, oacc[wt][nt2][1] * inv,
                        oacc[wt][nt2][2] * inv, oacc[wt][nt2][3] * inv);
        }
    __syncthreads();
    int rsub = tid >> 3, blk = tid & 7;
#pragma unroll
    for (int p = 0; p < 4; ++p) {
        int row = p * 32 + rsub;   // n_local 0..127
        int4 d = *(const int4*)&sT[row * 64 + ((blk ^ (row & 7)) * 8)];
        *(int4*)&Opart[((size_t)s * kB * kN + (size_t)b * kN + n0 + row) * kOC
                       + h * 64 + blk * 8] = d;
    }
}

// ---------------- final projection, fused split-combine, dbuf 1-barrier ----
__global__ __launch_bounds__(128, 3) void proj_kernel(
    const ushort* __restrict__ Opart, const float* __restrict__ Ls,
    const ushort* __restrict__ Wfb,
    const float* __restrict__ bf_, const float* __restrict__ sf,
    const float* __restrict__ bff, float* __restrict__ out)
{
    const int nt = blockIdx.x;
    const int ot = blockIdx.y;
    const int b  = blockIdx.z;
    __shared__ __align__(16) ushort sA[2][64 * 64];
    __shared__ __align__(16) ushort sB[2][64 * 64];
    const int tid = threadIdx.x;
    const int lane = tid & 63, wav = tid >> 6;
    const int quad = lane >> 4, l16 = lane & 15;

    const ushort* Wt  = Wfb + (size_t)(ot * 64) * kOC;
    const ushort* Op1 = Opart;
    const ushort* Op2 = Opart + (size_t)kB * kN * kOC;
    const size_t soff = (size_t)kB * kHeads * kN;

    f32x4 acc[4][2];
#pragma unroll
    for (int mt = 0; mt < 4; ++mt)
#pragma unroll
        for (int ntt = 0; ntt < 2; ++ntt)
#pragma unroll
            for (int r = 0; r < 4; ++r) acc[mt][ntt][r] = 0.f;

    int4 areg[4], b1reg[4], b2reg[4];
    float w1a[4], w2a[4];

    auto prefetch = [&](int kt) {
        int k0 = kt * 64;
#pragma unroll
        for (int p = 0; p < 4; ++p) {
            int idx = p * 128 + tid, row = idx >> 3, blk = idx & 7;
            areg[p] = *(const int4*)(Wt + (size_t)row * kOC + k0 + blk * 8);
            int n = nt * 64 + row;
            size_t bo = ((size_t)b * kN + n) * kOC + k0 + blk * 8;
            b1reg[p] = *(const int4*)(Op1 + bo);
            b2reg[p] = *(const int4*)(Op2 + bo);
            size_t si = ((size_t)b * kHeads + kt) * kN + n;
            float l1 = Ls[si], l2 = Ls[si + soff];
            float inv = 1.f / (l1 + l2);
            w1a[p] = l1 * inv; w2a[p] = l2 * inv;
        }
    };
    auto stage = [&](int buf) {
#pragma unroll
        for (int p = 0; p < 4; ++p) {
            int idx = p * 128 + tid, row = idx >> 3, blk = idx & 7;
            *(int4*)&sA[buf][row * 64 + ((blk ^ (row & 7)) * 8)] = areg[p];
            union { int4 v; ushort u[8]; } a, c;
            a.v = b1reg[p]; c.v = b2reg[p];
            float rr[8];
#pragma unroll
            for (int j = 0; j < 8; ++j)
                rr[j] = bf2f(a.u[j]) * w1a[p] + bf2f(c.u[j]) * w2a[p];
            int4 o;
            o.x = (int)pk_bf16(rr[0], rr[1]);
            o.y = (int)pk_bf16(rr[2], rr[3]);
            o.z = (int)pk_bf16(rr[4], rr[5]);
            o.w = (int)pk_bf16(rr[6], rr[7]);
            *(int4*)&sB[buf][row * 64 + ((blk ^ (row & 7)) * 8)] = o;
        }
    };

    prefetch(0);
    stage(0);
    __syncthreads();

    for (int kt = 0; kt < 7; ++kt) {
        const int cur = kt & 1;
        const bool more = (kt < 6);
        if (more) prefetch(kt + 1);
#pragma unroll
        for (int ks = 0; ks < 2; ++ks) {
            bf16x8 bfr[2];
#pragma unroll
            for (int ntt = 0; ntt < 2; ++ntt) {
                int row = wav * 32 + ntt * 16 + l16;
                bfr[ntt] = *(const bf16x8*)&sB[cur][row * 64 + (((ks * 4 + quad) ^ (row & 7)) * 8)];
            }
#pragma unroll
            for (int mt = 0; mt < 4; ++mt) {
                int row = mt * 16 + l16;
                bf16x8 af = *(const bf16x8*)&sA[cur][row * 64 + (((ks * 4 + quad) ^ (row & 7)) * 8)];
#pragma unroll
                for (int ntt = 0; ntt < 2; ++ntt)
                    acc[mt][ntt] = __builtin_amdgcn_mfma_f32_16x16x32_bf16(
                        af, bfr[ntt], acc[mt][ntt], 0, 0, 0);
            }
        }
        if (more) stage(cur ^ 1);
        __syncthreads();
    }
#pragma unroll
    for (int mt = 0; mt < 4; ++mt)
#pragma unroll
        for (int r = 0; r < 4; ++r) {
            int o = ot * 64 + mt * 16 + quad * 4 + r;
            float bfv = bf_[o], sfv = sf[o], bffv = bff[o];
#pragma unroll
            for (int ntt = 0; ntt < 2; ++ntt) {
                int n = nt * 64 + wav * 32 + ntt * 16 + l16;
                float y = fmaf(acc[mt][ntt][r] + bfv, sfv, bffv);
                out[((size_t)b * kC + o) * kN + n] = y > 0.f ? y : 0.f;
            }
        }
}

extern "C" void kernel_launch(void* const* d_in, const int* in_sizes, int n_in,
                              void* d_out, int out_size, void* d_ws, size_t ws_size,
                              hipStream_t stream) {
    const float* x   = (const float*)d_in[0];
    const float* Wq  = (const float*)d_in[1];
    const float* sq  = (const float*)d_in[2];
    const float* bq  = (const float*)d_in[3];
    const float* Wk  = (const float*)d_in[4];
    const float* sk  = (const float*)d_in[5];
    const float* bk  = (const float*)d_in[6];
    const float* Wv  = (const float*)d_in[7];
    const float* sv  = (const float*)d_in[8];
    const float* bv  = (const float*)d_in[9];
    const float* Wf  = (const float*)d_in[10];
    const float* bf_ = (const float*)d_in[11];
    const float* sf  = (const float*)d_in[12];
    const float* bff = (const float*)d_in[13];
    float* out = (float*)d_out;

    char* ws = (char*)d_ws;
    ushort* xT  = (ushort*)(ws);                         // 4,194,304
    ushort* Wqb = (ushort*)(ws + 4194304);               // 131,072
    ushort* Wkb = (ushort*)(ws + 4325376);               // 131,072
    ushort* Wvb = (ushort*)(ws + 4456448);               // 131,072
    ushort* Wfb = (ushort*)(ws + 4587520);               // 229,376
    ushort* qT  = (ushort*)(ws + 4816896);               // 4,194,304
    ushort* kT  = (ushort*)(ws + 9011200);               // 4,194,304
    ushort* vB  = (ushort*)(ws + 13205504);              // 4,194,304
    ushort* Opart = (ushort*)(ws + 17399808);            // 14,680,064
    float*  Ls  = (float*)(ws + 32079872);               // 458,752

    cast_w_kernel<<<dim3(112, 4), 256, 0, stream>>>(Wq, Wk, Wv, Wf, Wqb, Wkb, Wvb, Wfb);
    transpose_kernel<<<dim3(kN / 64, kC / 64, kB), 256, 0, stream>>>(x, xT);
    qkv_kernel<<<dim3(kN / 128, kC / 128, kB * 3), 256, 0, stream>>>(
        xT, Wqb, Wkb, Wvb, sq, bq, sk, bk, sv, bv, qT, kT, vB);
    attn_kernel<<<dim3(kN / 128, kHeads, kB * kSplit), 256, 0, stream>>>(
        qT, kT, vB, Opart, Ls);
    proj_kernel<<<dim3(kN / 64, kC / 64, kB), 128, 0, stream>>>(
        Opart, Ls, Wfb, bf_, sf, bff, out);
}